// Round 2
// baseline (384.899 us; speedup 1.0000x reference)
//
#include <hip/hip_runtime.h>
#include <hip/hip_bf16.h>

typedef short bf16x8 __attribute__((ext_vector_type(8)));
typedef float f32x4 __attribute__((ext_vector_type(4)));
typedef _Float16 f16x2 __attribute__((ext_vector_type(2)));

static __device__ __forceinline__ unsigned short f2bf_rne(float f) {
    unsigned int u = __float_as_uint(f);
    u += 0x7fff + ((u >> 16) & 1);
    return (unsigned short)(u >> 16);
}
static __device__ __forceinline__ float bf2f(unsigned short h) {
    return __uint_as_float(((unsigned int)h) << 16);
}

// split one fp32 weight element into hi/lo bf16 at its fragment-ordered slot
// B-frag layout for mfma_f32_16x16x32_bf16: lane=quad*16+(n&15) holds k=kc*32+quad*8+j
static __device__ __forceinline__ void wsplit_one(const float* W, unsigned short* hi,
                                                  unsigned short* lo, int BN, int idx) {
    int k = idx / BN, n = idx % BN;
    float w = W[idx];
    unsigned short h = f2bf_rne(w);
    unsigned short l = f2bf_rne(w - bf2f(h));
    int CT = BN >> 4;
    int kc = k >> 5, quad = (k >> 3) & 3, j = k & 7;
    int ct = n >> 4, c = n & 15;
    int slot = (((kc * CT + ct) * 4 + quad) * 16 + c) * 8 + j;
    hi[slot] = h;
    lo[slot] = l;
}

// ===================== GEMM body (BM=64) =====================
// C is written QUARTER-MAJOR: t4[col>>5][node][col&31] fp16, so aggregation runs as
// dim-split XCD-pinned passes (3.2MB gather region resident in one XCD pair's L2s).

template<int BN>
static __device__ __forceinline__ void gemm_body(const float* __restrict__ A,
                        const unsigned short* __restrict__ Whi, const unsigned short* __restrict__ Wlo,
                        _Float16* __restrict__ C, int N, int blk,
                        unsigned short* AhiS, unsigned short* AloS) {
    constexpr int CT = BN / 16;
    const int tid = threadIdx.x;
    const int wave = tid >> 6;
    const int lane = tid & 63;
    const int quad = lane >> 4;
    const int c16 = lane & 15;
    const int row0 = blk * 64;

    f32x4 acc[CT];
    #pragma unroll
    for (int t = 0; t < CT; ++t) acc[t] = (f32x4){0.f, 0.f, 0.f, 0.f};

    for (int kc = 0; kc < 4; ++kc) {
        #pragma unroll
        for (int r = 0; r < 2; ++r) {
            int f4 = tid + r * 256;
            int arow = f4 >> 3;
            int c4 = f4 & 7;
            int grow = row0 + arow;
            float4 v = make_float4(0.f, 0.f, 0.f, 0.f);
            if (grow < N) v = *(const float4*)&A[(size_t)grow * 128 + kc * 32 + c4 * 4];
            unsigned short h0 = f2bf_rne(v.x), h1 = f2bf_rne(v.y), h2 = f2bf_rne(v.z), h3 = f2bf_rne(v.w);
            ushort4 hv = make_ushort4(h0, h1, h2, h3);
            ushort4 lv = make_ushort4(f2bf_rne(v.x - bf2f(h0)), f2bf_rne(v.y - bf2f(h1)),
                                      f2bf_rne(v.z - bf2f(h2)), f2bf_rne(v.w - bf2f(h3)));
            int q = c4 >> 1;
            int joff = (c4 & 1) * 4;
            int base = (q * 64 + arow) * 8 + joff;
            *(ushort4*)&AhiS[base] = hv;
            *(ushort4*)&AloS[base] = lv;
        }
        __syncthreads();

        int abase = (quad * 64 + wave * 16 + c16) * 8;
        bf16x8 ahi = *(const bf16x8*)&AhiS[abase];
        bf16x8 alo = *(const bf16x8*)&AloS[abase];

        #pragma unroll
        for (int ct = 0; ct < CT; ++ct) {
            size_t bslot = ((size_t)(kc * CT + ct) * 64 + lane) * 8;
            bf16x8 bhi = *(const bf16x8*)&Whi[bslot];
            bf16x8 blo = *(const bf16x8*)&Wlo[bslot];
            acc[ct] = __builtin_amdgcn_mfma_f32_16x16x32_bf16(ahi, bhi, acc[ct], 0, 0, 0);
            acc[ct] = __builtin_amdgcn_mfma_f32_16x16x32_bf16(ahi, blo, acc[ct], 0, 0, 0);
            acc[ct] = __builtin_amdgcn_mfma_f32_16x16x32_bf16(alo, bhi, acc[ct], 0, 0, 0);
        }
        __syncthreads();
    }

    #pragma unroll
    for (int ct = 0; ct < CT; ++ct) {
        int col = ct * 16 + c16;
        _Float16* Cq = C + (size_t)(col >> 5) * N * 32 + (col & 31);
        #pragma unroll
        for (int r = 0; r < 4; ++r) {
            int grow = row0 + wave * 16 + quad * 4 + r;
            if (grow < N) Cq[(size_t)grow * 32] = (_Float16)acc[ct][r];
        }
    }
}

// ===================== preprocessing =====================

__global__ __launch_bounds__(256) void k_count_wsplit(const int* __restrict__ dst, int* __restrict__ deg,
                          int* __restrict__ rank,
                          const float* __restrict__ W1, const float* __restrict__ W2, const float* __restrict__ W3,
                          unsigned short* __restrict__ W1hi, unsigned short* __restrict__ W1lo,
                          unsigned short* __restrict__ W2hi, unsigned short* __restrict__ W2lo,
                          unsigned short* __restrict__ W3hi, unsigned short* __restrict__ W3lo,
                          int E) {
    int e = blockIdx.x * blockDim.x + threadIdx.x;
    if (e < E) rank[e] = atomicAdd(&deg[dst[e]], 1);
    if (e < 128 * 128) {
        wsplit_one(W1, W1hi, W1lo, 128, e);
        wsplit_one(W2, W2hi, W2lo, 128, e);
    }
    if (e < 128 * 64) wsplit_one(W3, W3hi, W3lo, 64, e);
}

// single-kernel scan; also pre-fills out[] with bf (final agg's halves combine via atomicAdd)
__global__ __launch_bounds__(1024) void k_scan(const int* __restrict__ deg, float* __restrict__ dinv,
                                               int* __restrict__ row_start,
                                               float* __restrict__ outp, const float* __restrict__ bf,
                                               int N) {
    __shared__ int s[1024];
    __shared__ int wsum[16];
    __shared__ int prefix;
    const int t = threadIdx.x;
    const int base = blockIdx.x * 1024;

    {
        int v = 0;
        for (int j = t; j < base; j += 1024) v += deg[j];
        for (int off = 32; off > 0; off >>= 1) v += __shfl_down(v, off, 64);
        if ((t & 63) == 0) wsum[t >> 6] = v;
        __syncthreads();
        if (t == 0) {
            int acc = 0;
            #pragma unroll
            for (int k = 0; k < 16; ++k) acc += wsum[k];
            prefix = acc;
        }
    }

    int i = base + t;
    int v = 0;
    if (i < N) {
        v = deg[i];
        dinv[i] = rsqrtf((float)v + 1.0f);
        outp[i] = bf[0];
    }
    s[t] = v;
    __syncthreads();
    for (int off = 1; off < 1024; off <<= 1) {
        int x = (t >= off) ? s[t - off] : 0;
        __syncthreads();
        s[t] += x;
        __syncthreads();
    }
    if (i <= N) row_start[i] = prefix + s[t] - v;   // row_start[N] = E via deg-past-N = 0
}

// ===================== fused: layer-1 GEMM + CSR scatter =====================

__global__ __launch_bounds__(256, 2) void k_gemm1_scatter(const float* __restrict__ A,
                          const unsigned short* __restrict__ Whi, const unsigned short* __restrict__ Wlo,
                          _Float16* __restrict__ C, int N, int gemmGrid,
                          const int* __restrict__ src, const int* __restrict__ dst,
                          const int* __restrict__ row_start, const int* __restrict__ rank,
                          const float* __restrict__ dinv, int2* __restrict__ cv, int E) {
    __shared__ unsigned short AhiS[4 * 64 * 8];
    __shared__ unsigned short AloS[4 * 64 * 8];
    if ((int)blockIdx.x < gemmGrid) {
        gemm_body<128>(A, Whi, Wlo, C, N, blockIdx.x, AhiS, AloS);
    } else {
        int e = (blockIdx.x - gemmGrid) * 256 + threadIdx.x;
        if (e < E) {
            int d = dst[e];
            int s = src[e];
            cv[row_start[d] + rank[e]] = make_int2(s, __float_as_int(dinv[s]));
        }
    }
}

template<int BN>
__global__ __launch_bounds__(256, 2) void k_gemm_mfma(const float* __restrict__ A,
                        const unsigned short* __restrict__ Whi, const unsigned short* __restrict__ Wlo,
                        _Float16* __restrict__ C, int N) {
    __shared__ unsigned short AhiS[4 * 64 * 8];
    __shared__ unsigned short AloS[4 * 64 * 8];
    gemm_body<BN>(A, Whi, Wlo, C, N, blockIdx.x, AhiS, AloS);
}

// ===================== aggregation (R13: XCD-PINNED dim-quartered passes) =====================
// blockIdx % 8 round-robins over the 8 XCDs (T1 premise). Quarter q is handled ONLY by
// blocks with (b&7)>>1 == q, i.e. XCD pair {2q, 2q+1}. Each XCD gathers E/2 edges x 64B
// against a fixed 3.2MB quarter region -> per-XCD L2 reuse = 8x (structural, not timing-based).
// Group-of-16 lanes per edge row (64B); headers broadcast via bpermute (__shfl, lane-varying
// group index); round-robin edge->group assignment keeps waste <=3 gathers per chunk.
// Output stores nontemporal so streaming writes don't evict the hot t-region from L2.

__global__ __launch_bounds__(256) void k_agg128q(const _Float16* __restrict__ t, float* __restrict__ outp,
                      const int* __restrict__ row_start, const int2* __restrict__ cv,
                      const float* __restrict__ dinv, const float* __restrict__ bias,
                      int N) {
    int b = blockIdx.x;
    int sub = b & 7;
    int q = sub >> 1;                         // quarter = XCD pair
    int nb = ((b >> 3) << 1) | (sub & 1);     // node-block within quarter, [0,12500)
    int node = nb * 4 + (threadIdx.x >> 6);
    int lane = threadIdx.x & 63;
    int l16 = lane & 15;
    int g4 = lane >> 4;
    const f16x2* tp = (const f16x2*)(t + (size_t)q * (size_t)N * 32);
    int p = row_start[node];
    int end = row_start[node + 1];
    float ax = 0.f, ay = 0.f;

    while (p < end) {
        int idx = p + lane;
        int2 h = (idx < end) ? cv[idx] : make_int2(0, 0);   // invalid lanes: s=0, w=0
        int cnt = end - p; cnt = cnt > 64 ? 64 : cnt;
        int jmax = (cnt + 3) >> 2;
        #pragma unroll 4
        for (int j = 0; j < jmax; ++j) {
            int sl = j * 4 + g4;                            // edge p+j*4+g4 -> this group
            int s = __shfl(h.x, sl, 64);
            float w = __int_as_float(__shfl(h.y, sl, 64));
            f16x2 v = tp[(size_t)s * 16 + l16];
            ax += w * (float)v.x;
            ay += w * (float)v.y;
        }
        p += 64;
    }
    ax += __shfl_xor(ax, 16, 64); ax += __shfl_xor(ax, 32, 64);
    ay += __shfl_xor(ay, 16, 64); ay += __shfl_xor(ay, 32, 64);

    float di = dinv[node];
    f16x2 sv = tp[(size_t)node * 16 + l16];
    float2 bv = ((const float2*)bias)[q * 16 + l16];
    float rx = fmaxf(di * ax + di * di * (float)sv.x + bv.x, 0.f);
    float ry = fmaxf(di * ay + di * di * (float)sv.y + bv.y, 0.f);
    if (g4 == 0) {
        unsigned long long rv = ((unsigned long long)__float_as_uint(ry) << 32) | __float_as_uint(rx);
        __builtin_nontemporal_store(rv,
            (unsigned long long*)&((float2*)outp)[(size_t)node * 64 + q * 16 + l16]);
    }
}

// layer-3 aggregation: D=64 split into 2 halves, half h pinned to XCD quad {4h..4h+3}
// (per-XCD reuse 4x); fused final linear; halves combine via atomicAdd into bf-prefilled out.
__global__ __launch_bounds__(256) void k_agg64_final(const _Float16* __restrict__ t, float* __restrict__ outp,
                      const int* __restrict__ row_start, const int2* __restrict__ cv,
                      const float* __restrict__ dinv, const float* __restrict__ bias,
                      const float* __restrict__ Wf,
                      int N) {
    int b = blockIdx.x;
    int sub = b & 7;
    int q = sub >> 2;                         // half = XCD quad
    int hb = ((b >> 3) << 2) | (sub & 3);     // node-block within half, [0,12500)
    int node = hb * 4 + (threadIdx.x >> 6);
    int lane = threadIdx.x & 63;
    int l16 = lane & 15;
    int g4 = lane >> 4;
    const f16x2* tp = (const f16x2*)(t + (size_t)q * (size_t)N * 32);
    int p = row_start[node];
    int end = row_start[node + 1];
    float ax = 0.f, ay = 0.f;

    while (p < end) {
        int idx = p + lane;
        int2 h = (idx < end) ? cv[idx] : make_int2(0, 0);
        int cnt = end - p; cnt = cnt > 64 ? 64 : cnt;
        int jmax = (cnt + 3) >> 2;
        #pragma unroll 4
        for (int j = 0; j < jmax; ++j) {
            int sl = j * 4 + g4;
            int s = __shfl(h.x, sl, 64);
            float w = __int_as_float(__shfl(h.y, sl, 64));
            f16x2 v = tp[(size_t)s * 16 + l16];
            ax += w * (float)v.x;
            ay += w * (float)v.y;
        }
        p += 64;
    }
    ax += __shfl_xor(ax, 16, 64); ax += __shfl_xor(ax, 32, 64);
    ay += __shfl_xor(ay, 16, 64); ay += __shfl_xor(ay, 32, 64);

    float di = dinv[node];
    f16x2 sv = tp[(size_t)node * 16 + l16];
    float2 bv = ((const float2*)bias)[q * 16 + l16];
    float rx = fmaxf(di * ax + di * di * (float)sv.x + bv.x, 0.f);
    float ry = fmaxf(di * ay + di * di * (float)sv.y + bv.y, 0.f);
    float2 wf = ((const float2*)Wf)[q * 16 + l16];
    float partial = rx * wf.x + ry * wf.y;
    partial += __shfl_xor(partial, 1, 64);
    partial += __shfl_xor(partial, 2, 64);
    partial += __shfl_xor(partial, 4, 64);
    partial += __shfl_xor(partial, 8, 64);
    if (lane == 0) atomicAdd(&outp[node], partial);
}

// ===================== launch =====================

extern "C" void kernel_launch(void* const* d_in, const int* in_sizes, int n_in,
                              void* d_out, int out_size, void* d_ws, size_t ws_size,
                              hipStream_t stream) {
    const float* x  = (const float*)d_in[0];
    const int*   src = (const int*)d_in[1];
    const int*   dst = (const int*)d_in[2];
    const float* W1 = (const float*)d_in[3];
    const float* b1 = (const float*)d_in[4];
    const float* W2 = (const float*)d_in[5];
    const float* b2 = (const float*)d_in[6];
    const float* W3 = (const float*)d_in[7];
    const float* b3 = (const float*)d_in[8];
    const float* Wf = (const float*)d_in[9];
    const float* bf = (const float*)d_in[10];
    float* out = (float*)d_out;

    const int N = 50000;
    const int E = 800000;

    char* ws = (char*)d_ws;
    size_t off = 0;
    auto alloc = [&](size_t bytes) -> void* {
        void* p = (void*)(ws + off);
        off += (bytes + 511) & ~((size_t)511);
        return p;
    };
    int*   deg       = (int*)alloc((size_t)N * 4);
    float* dinv      = (float*)alloc((size_t)N * 4);
    int*   row_start = (int*)alloc((size_t)(N + 1) * 4);
    int*   rank      = (int*)alloc((size_t)E * 4);
    int2*  cv        = (int2*)alloc((size_t)E * 8);
    _Float16* bufT   = (_Float16*)alloc((size_t)N * 128 * 2);   // GEMM out, quarter-major fp16
    float* bufH      = (float*)alloc((size_t)N * 128 * 4);      // agg out (GEMM input), fp32
    unsigned short* W1hi = (unsigned short*)alloc(128 * 128 * 2);
    unsigned short* W1lo = (unsigned short*)alloc(128 * 128 * 2);
    unsigned short* W2hi = (unsigned short*)alloc(128 * 128 * 2);
    unsigned short* W2lo = (unsigned short*)alloc(128 * 128 * 2);
    unsigned short* W3hi = (unsigned short*)alloc(128 * 64 * 2);
    unsigned short* W3lo = (unsigned short*)alloc(128 * 64 * 2);

    hipMemsetAsync(deg, 0, (size_t)N * 4, stream);

    k_count_wsplit<<<(E + 255) / 256, 256, 0, stream>>>(dst, deg, rank, W1, W2, W3,
                                                        W1hi, W1lo, W2hi, W2lo, W3hi, W3lo, E);
    int NB = (N + 1023) / 1024;   // 49 blocks
    k_scan<<<NB, 1024, 0, stream>>>(deg, dinv, row_start, out, bf, N);

    int gemmGrid = (N + 63) / 64;          // 782
    int scatGrid = (E + 255) / 256;        // 3125
    int agg128Grid = N;                    // 50000 blocks: (quarter = b&7>>1, 4 nodes/block)
    int agg64Grid  = N / 2;                // 25000 blocks: (half = b&7>>2, 4 nodes/block)

    // fused: layer-1 GEMM + scatter (independent work overlapped)
    k_gemm1_scatter<<<gemmGrid + scatGrid, 256, 0, stream>>>(x, W1hi, W1lo, bufT, N, gemmGrid,
                                                             src, dst, row_start, rank, dinv, cv, E);
    k_agg128q<<<agg128Grid, 256, 0, stream>>>(bufT, bufH, row_start, cv, dinv, b1, N);
    // layer 2
    k_gemm_mfma<128><<<gemmGrid, 256, 0, stream>>>(bufH, W2hi, W2lo, bufT, N);
    k_agg128q<<<agg128Grid, 256, 0, stream>>>(bufT, bufH, row_start, cv, dinv, b2, N);
    // layer 3 (transform to 64 dims first, then split-half aggregate + fused final linear)
    k_gemm_mfma<64><<<gemmGrid, 256, 0, stream>>>(bufH, W3hi, W3lo, bufT, N);
    k_agg64_final<<<agg64Grid, 256, 0, stream>>>(bufT, out, row_start, cv, dinv, b3, Wf, N);
}

// Round 3
// 273.431 us; speedup vs baseline: 1.4077x; 1.4077x over previous
//
#include <hip/hip_runtime.h>
#include <hip/hip_bf16.h>

typedef short bf16x8 __attribute__((ext_vector_type(8)));
typedef float f32x4 __attribute__((ext_vector_type(4)));
typedef _Float16 f16x2 __attribute__((ext_vector_type(2)));
typedef unsigned short u16x8 __attribute__((ext_vector_type(8)));

static __device__ __forceinline__ unsigned short f2bf_rne(float f) {
    unsigned int u = __float_as_uint(f);
    u += 0x7fff + ((u >> 16) & 1);
    return (unsigned short)(u >> 16);
}
static __device__ __forceinline__ float bf2f(unsigned short h) {
    return __uint_as_float(((unsigned int)h) << 16);
}

// split one fp32 weight element into hi/lo bf16 at its fragment-ordered slot
// B-frag layout for mfma_f32_16x16x32_bf16: lane=quad*16+(n&15) holds k=kc*32+quad*8+j
static __device__ __forceinline__ void wsplit_one(const float* W, unsigned short* hi,
                                                  unsigned short* lo, int BN, int idx) {
    int k = idx / BN, n = idx % BN;
    float w = W[idx];
    unsigned short h = f2bf_rne(w);
    unsigned short l = f2bf_rne(w - bf2f(h));
    int CT = BN >> 4;
    int kc = k >> 5, quad = (k >> 3) & 3, j = k & 7;
    int ct = n >> 4, c = n & 15;
    int slot = (((kc * CT + ct) * 4 + quad) * 16 + c) * 8 + j;
    hi[slot] = h;
    lo[slot] = l;
}

// ===================== GEMM bodies (BM=64; 782 blocks balance across 256 CUs) ==========
// R14: layers 2/3 read A as PRE-SPLIT bf16 hi/lo planes written by the agg epilogue
// (same total bytes as the old fp32 buffer, but staging needs ZERO conversion VALU and
// the MFMA operands are bit-identical to the old on-the-fly split).

// layer-1 variant: A is external fp32 x, split during staging (original R0 path)
template<int BN>
static __device__ __forceinline__ void gemm_body_f32(const float* __restrict__ A,
                        const unsigned short* __restrict__ Whi, const unsigned short* __restrict__ Wlo,
                        _Float16* __restrict__ C, int N, int blk,
                        unsigned short* AhiS, unsigned short* AloS) {
    constexpr int CT = BN / 16;
    const int tid = threadIdx.x;
    const int wave = tid >> 6;
    const int lane = tid & 63;
    const int quad = lane >> 4;
    const int c16 = lane & 15;
    const int row0 = blk * 64;

    f32x4 acc[CT];
    #pragma unroll
    for (int t = 0; t < CT; ++t) acc[t] = (f32x4){0.f, 0.f, 0.f, 0.f};

    for (int kc = 0; kc < 4; ++kc) {
        #pragma unroll
        for (int r = 0; r < 2; ++r) {
            int f4 = tid + r * 256;
            int arow = f4 >> 3;
            int c4 = f4 & 7;
            int grow = row0 + arow;
            float4 v = make_float4(0.f, 0.f, 0.f, 0.f);
            if (grow < N) v = *(const float4*)&A[(size_t)grow * 128 + kc * 32 + c4 * 4];
            unsigned short h0 = f2bf_rne(v.x), h1 = f2bf_rne(v.y), h2 = f2bf_rne(v.z), h3 = f2bf_rne(v.w);
            ushort4 hv = make_ushort4(h0, h1, h2, h3);
            ushort4 lv = make_ushort4(f2bf_rne(v.x - bf2f(h0)), f2bf_rne(v.y - bf2f(h1)),
                                      f2bf_rne(v.z - bf2f(h2)), f2bf_rne(v.w - bf2f(h3)));
            int q = c4 >> 1;
            int joff = (c4 & 1) * 4;
            int base = (q * 64 + arow) * 8 + joff;
            *(ushort4*)&AhiS[base] = hv;
            *(ushort4*)&AloS[base] = lv;
        }
        __syncthreads();

        int abase = (quad * 64 + wave * 16 + c16) * 8;
        bf16x8 ahi = *(const bf16x8*)&AhiS[abase];
        bf16x8 alo = *(const bf16x8*)&AloS[abase];

        #pragma unroll
        for (int ct = 0; ct < CT; ++ct) {
            size_t bslot = ((size_t)(kc * CT + ct) * 64 + lane) * 8;
            bf16x8 bhi = *(const bf16x8*)&Whi[bslot];
            bf16x8 blo = *(const bf16x8*)&Wlo[bslot];
            acc[ct] = __builtin_amdgcn_mfma_f32_16x16x32_bf16(ahi, bhi, acc[ct], 0, 0, 0);
            acc[ct] = __builtin_amdgcn_mfma_f32_16x16x32_bf16(ahi, blo, acc[ct], 0, 0, 0);
            acc[ct] = __builtin_amdgcn_mfma_f32_16x16x32_bf16(alo, bhi, acc[ct], 0, 0, 0);
        }
        __syncthreads();
    }

    #pragma unroll
    for (int ct = 0; ct < CT; ++ct) {
        #pragma unroll
        for (int r = 0; r < 4; ++r) {
            int grow = row0 + wave * 16 + quad * 4 + r;
            if (grow < N) C[(size_t)grow * BN + ct * 16 + c16] = (_Float16)acc[ct][r];
        }
    }
}

// layers-2/3 variant: A given as bf16 hi/lo planes [node][128]; staging is a pure copy.
// Thread tid -> (arow = tid>>2 in [0,64), cblk = tid&3): 16B = 8 contiguous bf16 of one row,
// k-local kl = cblk*8 + j  ->  LDS slot base (cblk*64 + arow)*8  (same fragment layout as f32 path).
template<int BN>
static __device__ __forceinline__ void gemm_body_bf(const unsigned short* __restrict__ Ahi,
                        const unsigned short* __restrict__ Alo,
                        const unsigned short* __restrict__ Whi, const unsigned short* __restrict__ Wlo,
                        _Float16* __restrict__ C, int N, int blk,
                        unsigned short* AhiS, unsigned short* AloS) {
    constexpr int CT = BN / 16;
    const int tid = threadIdx.x;
    const int wave = tid >> 6;
    const int lane = tid & 63;
    const int quad = lane >> 4;
    const int c16 = lane & 15;
    const int row0 = blk * 64;
    const int arow = tid >> 2;
    const int cblk = tid & 3;
    const int grow = row0 + arow;
    const bool inb = grow < N;
    const size_t agbase = (size_t)grow * 128 + cblk * 8;
    const int sbase = (cblk * 64 + arow) * 8;

    f32x4 acc[CT];
    #pragma unroll
    for (int t = 0; t < CT; ++t) acc[t] = (f32x4){0.f, 0.f, 0.f, 0.f};

    for (int kc = 0; kc < 4; ++kc) {
        u16x8 hv = {0, 0, 0, 0, 0, 0, 0, 0};
        u16x8 lv = {0, 0, 0, 0, 0, 0, 0, 0};
        if (inb) {
            hv = *(const u16x8*)&Ahi[agbase + kc * 32];
            lv = *(const u16x8*)&Alo[agbase + kc * 32];
        }
        *(u16x8*)&AhiS[sbase] = hv;
        *(u16x8*)&AloS[sbase] = lv;
        __syncthreads();

        int abase = (quad * 64 + wave * 16 + c16) * 8;
        bf16x8 ahi = *(const bf16x8*)&AhiS[abase];
        bf16x8 alo = *(const bf16x8*)&AloS[abase];

        #pragma unroll
        for (int ct = 0; ct < CT; ++ct) {
            size_t bslot = ((size_t)(kc * CT + ct) * 64 + lane) * 8;
            bf16x8 bhi = *(const bf16x8*)&Whi[bslot];
            bf16x8 blo = *(const bf16x8*)&Wlo[bslot];
            acc[ct] = __builtin_amdgcn_mfma_f32_16x16x32_bf16(ahi, bhi, acc[ct], 0, 0, 0);
            acc[ct] = __builtin_amdgcn_mfma_f32_16x16x32_bf16(ahi, blo, acc[ct], 0, 0, 0);
            acc[ct] = __builtin_amdgcn_mfma_f32_16x16x32_bf16(alo, bhi, acc[ct], 0, 0, 0);
        }
        __syncthreads();
    }

    #pragma unroll
    for (int ct = 0; ct < CT; ++ct) {
        #pragma unroll
        for (int r = 0; r < 4; ++r) {
            int gr = row0 + wave * 16 + quad * 4 + r;
            if (gr < N) C[(size_t)gr * BN + ct * 16 + c16] = (_Float16)acc[ct][r];
        }
    }
}

// ===================== preprocessing =====================

__global__ __launch_bounds__(256) void k_count_wsplit(const int* __restrict__ dst, int* __restrict__ deg,
                          int* __restrict__ rank,
                          const float* __restrict__ W1, const float* __restrict__ W2, const float* __restrict__ W3,
                          unsigned short* __restrict__ W1hi, unsigned short* __restrict__ W1lo,
                          unsigned short* __restrict__ W2hi, unsigned short* __restrict__ W2lo,
                          unsigned short* __restrict__ W3hi, unsigned short* __restrict__ W3lo,
                          int E) {
    int e = blockIdx.x * blockDim.x + threadIdx.x;
    if (e < E) rank[e] = atomicAdd(&deg[dst[e]], 1);
    if (e < 128 * 128) {
        wsplit_one(W1, W1hi, W1lo, 128, e);
        wsplit_one(W2, W2hi, W2lo, 128, e);
    }
    if (e < 128 * 64) wsplit_one(W3, W3hi, W3lo, 64, e);
}

__global__ __launch_bounds__(1024) void k_scan(const int* __restrict__ deg, float* __restrict__ dinv,
                                               int* __restrict__ row_start, int N) {
    __shared__ int s[1024];
    __shared__ int wsum[16];
    __shared__ int prefix;
    const int t = threadIdx.x;
    const int base = blockIdx.x * 1024;

    {
        int v = 0;
        for (int j = t; j < base; j += 1024) v += deg[j];
        for (int off = 32; off > 0; off >>= 1) v += __shfl_down(v, off, 64);
        if ((t & 63) == 0) wsum[t >> 6] = v;
        __syncthreads();
        if (t == 0) {
            int acc = 0;
            #pragma unroll
            for (int k = 0; k < 16; ++k) acc += wsum[k];
            prefix = acc;
        }
    }

    int i = base + t;
    int v = 0;
    if (i < N) {
        v = deg[i];
        dinv[i] = rsqrtf((float)v + 1.0f);
    }
    s[t] = v;
    __syncthreads();
    for (int off = 1; off < 1024; off <<= 1) {
        int x = (t >= off) ? s[t - off] : 0;
        __syncthreads();
        s[t] += x;
        __syncthreads();
    }
    if (i <= N) row_start[i] = prefix + s[t] - v;   // row_start[N] = E via deg-past-N = 0
}

// ===================== fused: layer-1 GEMM + CSR scatter (independent work) =====================

__global__ __launch_bounds__(256, 2) void k_gemm1_scatter(const float* __restrict__ A,
                          const unsigned short* __restrict__ Whi, const unsigned short* __restrict__ Wlo,
                          _Float16* __restrict__ C, int N, int gemmGrid,
                          const int* __restrict__ src, const int* __restrict__ dst,
                          const int* __restrict__ row_start, const int* __restrict__ rank,
                          const float* __restrict__ dinv, int2* __restrict__ cv, int E) {
    __shared__ unsigned short AhiS[4 * 64 * 8];
    __shared__ unsigned short AloS[4 * 64 * 8];
    if ((int)blockIdx.x < gemmGrid) {
        gemm_body_f32<128>(A, Whi, Wlo, C, N, blockIdx.x, AhiS, AloS);
    } else {
        int e = (blockIdx.x - gemmGrid) * 256 + threadIdx.x;
        if (e < E) {
            int d = dst[e];
            int s = src[e];
            cv[row_start[d] + rank[e]] = make_int2(s, __float_as_int(dinv[s]));
        }
    }
}

// layers 2/3: bf16-plane input GEMM
template<int BN>
__global__ __launch_bounds__(256, 2) void k_gemm_bf(const unsigned short* __restrict__ Ahi,
                        const unsigned short* __restrict__ Alo,
                        const unsigned short* __restrict__ Whi, const unsigned short* __restrict__ Wlo,
                        _Float16* __restrict__ C, int N) {
    __shared__ unsigned short AhiS[4 * 64 * 8];
    __shared__ unsigned short AloS[4 * 64 * 8];
    gemm_body_bf<BN>(Ahi, Alo, Whi, Wlo, C, N, blockIdx.x, AhiS, AloS);
}

// ===================== aggregation (R0 structure — proven fastest) =====================
// One wave per node; header broadcast via readlane (SGPR, no DS ops); masked full-depth
// rounds of 16 gathers. t is fp16 (halves random-gather bytes). Pinned at random-gather
// ceiling (~3.7 TB/s); R12/R13 dim-split variants both regressed (per-edge overhead x4).
// R14 delta: epilogue writes hi/lo bf16 planes (pre-split for the next GEMM) instead of fp32.

__global__ __launch_bounds__(256) void k_agg128(const _Float16* __restrict__ t,
                      unsigned short* __restrict__ outHi, unsigned short* __restrict__ outLo,
                      const int* __restrict__ row_start, const int2* __restrict__ cv,
                      const float* __restrict__ dinv, const float* __restrict__ bias,
                      int N) {
    int gid = blockIdx.x * blockDim.x + threadIdx.x;
    int node = gid >> 6;
    int lane = gid & 63;
    if (node >= N) return;
    int p = row_start[node];
    int end = row_start[node + 1];
    const f16x2* tp = (const f16x2*)t;
    float2 acc[4];
    #pragma unroll
    for (int j = 0; j < 4; ++j) acc[j] = make_float2(0.f, 0.f);

    while (p < end) {
        int idx = p + lane;
        int2 h = (idx < end) ? cv[idx] : make_int2(0, 0);   // invalid lanes: s=0, w=0
        int cnt = min(end - p, 64);
        int rounds = (cnt + 15) >> 4;
        for (int r = 0; r < rounds; ++r) {
            int base = r * 16;
            int s[16]; float w[16];
            #pragma unroll
            for (int j = 0; j < 16; ++j) {
                s[j] = __builtin_amdgcn_readlane(h.x, base + j);
                w[j] = __int_as_float(__builtin_amdgcn_readlane(h.y, base + j));
            }
            f16x2 v[16];
            #pragma unroll
            for (int j = 0; j < 16; ++j) v[j] = tp[s[j] * 64 + lane];
            #pragma unroll
            for (int j = 0; j < 16; ++j) {
                acc[j & 3].x += w[j] * (float)v[j].x;   // v_fma_mix_f32
                acc[j & 3].y += w[j] * (float)v[j].y;
            }
        }
        p += 64;
    }
    float di = dinv[node];
    f16x2 sv = tp[node * 64 + lane];
    float2 bv = ((const float2*)bias)[lane];
    float sx = (acc[0].x + acc[1].x) + (acc[2].x + acc[3].x);
    float sy = (acc[0].y + acc[1].y) + (acc[2].y + acc[3].y);
    float rx = fmaxf(di * sx + di * di * (float)sv.x + bv.x, 0.f);
    float ry = fmaxf(di * sy + di * di * (float)sv.y + bv.y, 0.f);
    // pre-split for next GEMM (bit-identical to splitting at staging time)
    unsigned short hx = f2bf_rne(rx), hy = f2bf_rne(ry);
    unsigned short lx = f2bf_rne(rx - bf2f(hx)), ly = f2bf_rne(ry - bf2f(hy));
    ushort2 hw; hw.x = hx; hw.y = hy;
    ushort2 lw; lw.x = lx; lw.y = ly;
    ((ushort2*)outHi)[(size_t)node * 64 + lane] = hw;
    ((ushort2*)outLo)[(size_t)node * 64 + lane] = lw;
}

// layer-3 aggregation (D=64, fp16 t) fused with final linear: out[i] = relu(agg_i + b) . Wf + bf
__global__ __launch_bounds__(256) void k_agg64_final(const _Float16* __restrict__ t, float* __restrict__ outp,
                      const int* __restrict__ row_start, const int2* __restrict__ cv,
                      const float* __restrict__ dinv, const float* __restrict__ bias,
                      const float* __restrict__ Wf, const float* __restrict__ bf,
                      int N) {
    int gid = blockIdx.x * blockDim.x + threadIdx.x;
    int node = gid >> 6;
    int lane = gid & 63;
    if (node >= N) return;
    int p = row_start[node];
    int end = row_start[node + 1];
    float acc[4] = {0.f, 0.f, 0.f, 0.f};

    while (p < end) {
        int idx = p + lane;
        int2 h = (idx < end) ? cv[idx] : make_int2(0, 0);
        int cnt = min(end - p, 64);
        int rounds = (cnt + 15) >> 4;
        for (int r = 0; r < rounds; ++r) {
            int base = r * 16;
            int s[16]; float w[16];
            #pragma unroll
            for (int j = 0; j < 16; ++j) {
                s[j] = __builtin_amdgcn_readlane(h.x, base + j);
                w[j] = __int_as_float(__builtin_amdgcn_readlane(h.y, base + j));
            }
            _Float16 v[16];
            #pragma unroll
            for (int j = 0; j < 16; ++j) v[j] = t[s[j] * 64 + lane];
            #pragma unroll
            for (int j = 0; j < 16; ++j) acc[j & 3] += w[j] * (float)v[j];
        }
        p += 64;
    }
    float di = dinv[node];
    float r = di * ((acc[0] + acc[1]) + (acc[2] + acc[3])) + di * di * (float)t[node * 64 + lane] + bias[lane];
    r = fmaxf(r, 0.f);
    float v = r * Wf[lane];
    for (int off = 32; off > 0; off >>= 1) v += __shfl_down(v, off, 64);
    if (lane == 0) outp[node] = v + bf[0];
}

// ===================== launch =====================

extern "C" void kernel_launch(void* const* d_in, const int* in_sizes, int n_in,
                              void* d_out, int out_size, void* d_ws, size_t ws_size,
                              hipStream_t stream) {
    const float* x  = (const float*)d_in[0];
    const int*   src = (const int*)d_in[1];
    const int*   dst = (const int*)d_in[2];
    const float* W1 = (const float*)d_in[3];
    const float* b1 = (const float*)d_in[4];
    const float* W2 = (const float*)d_in[5];
    const float* b2 = (const float*)d_in[6];
    const float* W3 = (const float*)d_in[7];
    const float* b3 = (const float*)d_in[8];
    const float* Wf = (const float*)d_in[9];
    const float* bf = (const float*)d_in[10];
    float* out = (float*)d_out;

    const int N = 50000;
    const int E = 800000;

    char* ws = (char*)d_ws;
    size_t off = 0;
    auto alloc = [&](size_t bytes) -> void* {
        void* p = (void*)(ws + off);
        off += (bytes + 511) & ~((size_t)511);
        return p;
    };
    int*   deg       = (int*)alloc((size_t)N * 4);
    float* dinv      = (float*)alloc((size_t)N * 4);
    int*   row_start = (int*)alloc((size_t)(N + 1) * 4);
    int*   rank      = (int*)alloc((size_t)E * 4);
    int2*  cv        = (int2*)alloc((size_t)E * 8);
    _Float16* bufT   = (_Float16*)alloc((size_t)N * 128 * 2);        // GEMM out (gather source), fp16
    unsigned short* bufHi = (unsigned short*)alloc((size_t)N * 128 * 2);  // agg out hi-plane (GEMM A)
    unsigned short* bufLo = (unsigned short*)alloc((size_t)N * 128 * 2);  // agg out lo-plane (GEMM A)
    unsigned short* W1hi = (unsigned short*)alloc(128 * 128 * 2);
    unsigned short* W1lo = (unsigned short*)alloc(128 * 128 * 2);
    unsigned short* W2hi = (unsigned short*)alloc(128 * 128 * 2);
    unsigned short* W2lo = (unsigned short*)alloc(128 * 128 * 2);
    unsigned short* W3hi = (unsigned short*)alloc(128 * 64 * 2);
    unsigned short* W3lo = (unsigned short*)alloc(128 * 64 * 2);

    hipMemsetAsync(deg, 0, (size_t)N * 4, stream);

    k_count_wsplit<<<(E + 255) / 256, 256, 0, stream>>>(dst, deg, rank, W1, W2, W3,
                                                        W1hi, W1lo, W2hi, W2lo, W3hi, W3lo, E);
    int NB = (N + 1023) / 1024;   // 49 blocks
    k_scan<<<NB, 1024, 0, stream>>>(deg, dinv, row_start, N);

    int gemmGrid = (N + 63) / 64;          // 782
    int scatGrid = (E + 255) / 256;        // 3125
    int aggGrid = (N * 64 + 255) / 256;

    // fused: layer-1 GEMM + scatter (independent work overlapped, one node saved)
    k_gemm1_scatter<<<gemmGrid + scatGrid, 256, 0, stream>>>(x, W1hi, W1lo, bufT, N, gemmGrid,
                                                             src, dst, row_start, rank, dinv, cv, E);
    k_agg128<<<aggGrid, 256, 0, stream>>>(bufT, bufHi, bufLo, row_start, cv, dinv, b1, N);
    // layer 2
    k_gemm_bf<128><<<gemmGrid, 256, 0, stream>>>(bufHi, bufLo, W2hi, W2lo, bufT, N);
    k_agg128<<<aggGrid, 256, 0, stream>>>(bufT, bufHi, bufLo, row_start, cv, dinv, b2, N);
    // layer 3 (transform to 64 dims first, then aggregate + fused final linear)
    k_gemm_bf<64><<<gemmGrid, 256, 0, stream>>>(bufHi, bufLo, W3hi, W3lo, bufT, N);
    k_agg64_final<<<aggGrid, 256, 0, stream>>>(bufT, out, row_start, cv, dinv, b3, Wf, bf, N);
}